// Round 10
// baseline (148.288 us; speedup 1.0000x reference)
//
#include <hip/hip_runtime.h>

#define NODES 512
#define WORDS 16          // 512 bits / 32
#define NBATCH 32
#define SENTINEL 11       // MAX_DISTANCE + 1
#define NEMB 12           // MAX_DISTANCE + 2
#define NOUT 8
#define G 8               // sources per block: 128 KB stores per 32 KB row-read

// ---------------------------------------------------------------------------
// K1: pack adjacency bits, one u32 word (32 elements, 8x float4) per thread.
// node_mask (int32 on upload) ballot-packed into LDS once per block.
// ---------------------------------------------------------------------------
__global__ void __launch_bounds__(256)
pack_bits(const float* __restrict__ A, const int* __restrict__ mask,
          unsigned int* __restrict__ bitA) {
    const int tid = blockIdx.x * 256 + threadIdx.x;   // 262144 words total
    const int t = threadIdx.x;
    const int w = tid & 15;
    const int i = (tid >> 4) & 511;
    const int b = tid >> 13;                          // constant per block

    __shared__ unsigned int s_mw[WORDS];
    {
        bool m0 = mask[b * NODES + t] != 0;
        bool m1 = mask[b * NODES + 256 + t] != 0;
        unsigned long long b0 = __ballot(m0);
        unsigned long long b1 = __ballot(m1);
        if ((t & 63) == 0) {
            int wv = t >> 6;
            s_mw[2 * wv]         = (unsigned int)b0;
            s_mw[2 * wv + 1]     = (unsigned int)(b0 >> 32);
            s_mw[8 + 2 * wv]     = (unsigned int)b1;
            s_mw[8 + 2 * wv + 1] = (unsigned int)(b1 >> 32);
        }
    }

    const float4* p = (const float4*)(A + (size_t)tid * 32);
    unsigned int bits = 0;
#pragma unroll
    for (int q = 0; q < 8; ++q) {
        float4 v = p[q];
        bits |= (v.x > 0.5f ? 1u : 0u) << (4 * q);
        bits |= (v.y > 0.5f ? 1u : 0u) << (4 * q + 1);
        bits |= (v.z > 0.5f ? 1u : 0u) << (4 * q + 2);
        bits |= (v.w > 0.5f ? 1u : 0u) << (4 * q + 3);
    }
    __syncthreads();
    bool rv = (s_mw[i >> 5] >> (i & 31)) & 1u;
    bitA[tid] = rv ? (bits & s_mw[w]) : 0u;
}

// ---------------------------------------------------------------------------
// K2: symmetrize: adj[b,i,w] |= transpose bits (1 MB, L2-resident).
// ---------------------------------------------------------------------------
__global__ void __launch_bounds__(256)
symmetrize(const unsigned int* __restrict__ bitA, unsigned int* __restrict__ adjb) {
    int tid = blockIdx.x * 256 + threadIdx.x;   // total B*N*WORDS = 262144
    int w = tid & 15;
    int i = (tid >> 4) & 511;
    int b = tid >> 13;
    const unsigned int* base = bitA + (size_t)b * NODES * WORDS;
    unsigned int word = base[i * WORDS + w];
    unsigned int t = 0;
    int iw = i >> 5, ib = i & 31;
#pragma unroll
    for (int k = 0; k < 32; ++k) {
        t |= ((base[(32 * w + k) * WORDS + iw] >> ib) & 1u) << k;
    }
    adjb[tid] = word | t;
}

// ---------------------------------------------------------------------------
// K3: direct d<=2 shortest-path + embedding store, G=8 sources per block.
// 256 threads; thread t handles columns t and t+256 SEQUENTIALLY (one
// adjacency row live at a time -> small VGPR set, (256,8) fits).
// Per block: 32 KB row reads amortized over 128 KB of stores (4:1; r9 was
// 1:2 and the scattered row loads gated every block). Grid = 2048 blocks =
// exactly 8/CU. Hot path: d1 = bit of s_rowi (LDS broadcast), d2 =
// row_c & row_i != 0; no BFS loop. Cold t>=3 fallback kept for correctness.
// ---------------------------------------------------------------------------
__global__ void __launch_bounds__(256, 8)
bfs_store(const unsigned int* __restrict__ adjb, const int* __restrict__ mask,
          const float* __restrict__ emb, float4* __restrict__ out4) {
    const int i0 = blockIdx.x * G;
    const int b = blockIdx.y;
    const int t = threadIdx.x;
    const int cA = t, cB = t + 256;

    __shared__ unsigned int s_rowi[G][WORDS];      // 512 B, source rows
    __shared__ unsigned int s_dw0[NODES];          // packed d, sources 0..3
    __shared__ unsigned int s_dw1[NODES];          // packed d, sources 4..7
    __shared__ unsigned int s_f[2][G][WORDS];      // frontier (fallback)
    __shared__ unsigned int s_state[2][4];
    __shared__ __align__(16) float s_emb[NEMB * NOUT];

    if (t < NEMB * NOUT) s_emb[t] = emb[t];

    const unsigned int* Ab = adjb + (size_t)b * NODES * WORDS;
    if (t < G * 4) {                               // 32 threads: 8 rows x 16B
        int s = t >> 2, q = t & 3;
        ((uint4*)s_rowi[s])[q] = ((const uint4*)(Ab + (size_t)(i0 + s) * WORDS))[q];
    }

    bool vs[G];                                    // wave-uniform -> SGPRs
#pragma unroll
    for (int s = 0; s < G; ++s) vs[s] = (mask[b * NODES + i0 + s] != 0);
    const bool validA = (mask[b * NODES + cA] != 0);
    const bool validB = (mask[b * NODES + cB] != 0);

    const uint4* rA = (const uint4*)(Ab + (size_t)cA * WORDS);
    const uint4* rB = (const uint4*)(Ab + (size_t)cB * WORDS);

    __syncthreads();   // s_rowi, s_emb visible

    unsigned int dwA0 = 0, dwA1 = 0, dwB0 = 0, dwB1 = 0;
    {   // column cA: one row live
        uint4 r0 = rA[0], r1 = rA[1], r2 = rA[2], r3 = rA[3];
#pragma unroll
        for (int s = 0; s < G; ++s) {
            const uint4* R = (const uint4*)s_rowi[s];   // broadcast reads
            uint4 R0 = R[0], R1 = R[1], R2 = R[2], R3 = R[3];
            unsigned int hit =
                (r0.x & R0.x) | (r0.y & R0.y) | (r0.z & R0.z) | (r0.w & R0.w) |
                (r1.x & R1.x) | (r1.y & R1.y) | (r1.z & R1.z) | (r1.w & R1.w) |
                (r2.x & R2.x) | (r2.y & R2.y) | (r2.z & R2.z) | (r2.w & R2.w) |
                (r3.x & R3.x) | (r3.y & R3.y) | (r3.z & R3.z) | (r3.w & R3.w);
            unsigned int bit1 = (s_rowi[s][cA >> 5] >> (cA & 31)) & 1u;
            unsigned int d = (cA == i0 + s && vs[s]) ? 0u
                             : (bit1 ? 1u : (hit ? 2u : (unsigned)SENTINEL));
            if (s < 4) dwA0 |= d << (8 * s); else dwA1 |= d << (8 * (s - 4));
        }
        s_dw0[cA] = dwA0; s_dw1[cA] = dwA1;
    }
    {   // column cB
        uint4 r0 = rB[0], r1 = rB[1], r2 = rB[2], r3 = rB[3];
#pragma unroll
        for (int s = 0; s < G; ++s) {
            const uint4* R = (const uint4*)s_rowi[s];
            uint4 R0 = R[0], R1 = R[1], R2 = R[2], R3 = R[3];
            unsigned int hit =
                (r0.x & R0.x) | (r0.y & R0.y) | (r0.z & R0.z) | (r0.w & R0.w) |
                (r1.x & R1.x) | (r1.y & R1.y) | (r1.z & R1.z) | (r1.w & R1.w) |
                (r2.x & R2.x) | (r2.y & R2.y) | (r2.z & R2.z) | (r2.w & R2.w) |
                (r3.x & R3.x) | (r3.y & R3.y) | (r3.z & R3.z) | (r3.w & R3.w);
            unsigned int bit1 = (s_rowi[s][cB >> 5] >> (cB & 31)) & 1u;
            unsigned int d = (cB == i0 + s && vs[s]) ? 0u
                             : (bit1 ? 1u : (hit ? 2u : (unsigned)SENTINEL));
            if (s < 4) dwB0 |= d << (8 * s); else dwB1 |= d << (8 * (s - 4));
        }
        s_dw0[cB] = dwB0; s_dw1[cB] = dwB1;
    }

    // consensus: seed d==2 frontier + saturation check
    {
        bool thr_done =
            (!validA || (((dwA0 | (dwA0 >> 16)) & 0x0808u) == 0 &&
                         ((dwA1 | (dwA1 >> 16)) & 0x0808u) == 0)) &&
            (!validB || (((dwB0 | (dwB0 >> 16)) & 0x0808u) == 0 &&
                         ((dwB1 | (dwB1 >> 16)) & 0x0808u) == 0));
        // d<=2 iff byte has bit3 clear (d in {0,1,2} vs 11=0b1011): bit3 set only for 11… 
        // 11 = 0x0B -> bit3 set; 0,1,2 -> bit3 clear. So done iff no byte has bit 3.
        unsigned long long balD = __ballot(thr_done);
        unsigned long long anyAcc = 0;
#pragma unroll
        for (int s = 0; s < G; ++s) {
            unsigned int dA = ((s < 4 ? dwA0 >> (8 * s) : dwA1 >> (8 * (s - 4))) & 0xffu);
            unsigned int dB = ((s < 4 ? dwB0 >> (8 * s) : dwB1 >> (8 * (s - 4))) & 0xffu);
            unsigned long long fA = __ballot(dA == 2u);
            unsigned long long fB = __ballot(dB == 2u);
            anyAcc |= fA | fB;
            if ((t & 63) == 0) {
                int wv = t >> 6;
                s_f[0][s][2 * wv]         = (unsigned int)fA;
                s_f[0][s][2 * wv + 1]     = (unsigned int)(fA >> 32);
                s_f[0][s][8 + 2 * wv]     = (unsigned int)fB;
                s_f[0][s][8 + 2 * wv + 1] = (unsigned int)(fB >> 32);
            }
        }
        if ((t & 63) == 0)
            s_state[0][t >> 6] = ((anyAcc != 0ull) ? 1u : 0u) |
                                 ((balD == ~0ull) ? 2u : 0u);
    }
    __syncthreads();
    unsigned int anyw = 0, donew = 2;
#pragma unroll
    for (int wv = 0; wv < 4; ++wv) {
        unsigned int st = s_state[0][wv];
        anyw |= st; donew &= st;
    }

    if ((anyw & 1u) && !(donew & 2u)) {
        // COLD fallback: general BFS t=3..10 (never runs for dense inputs).
        unsigned int reachA = 0, reachB = 0;
#pragma unroll
        for (int s = 0; s < G; ++s) {
            unsigned int dA = ((s < 4 ? dwA0 >> (8 * s) : dwA1 >> (8 * (s - 4))) & 0xffu);
            unsigned int dB = ((s < 4 ? dwB0 >> (8 * s) : dwB1 >> (8 * (s - 4))) & 0xffu);
            if (dA != (unsigned)SENTINEL) reachA |= 1u << s;
            if (dB != (unsigned)SENTINEL) reachB |= 1u << s;
        }
        int p = 0;
        for (int tt = 3; tt <= 10; ++tt) {
            uint4 a0 = rA[0], a1 = rA[1], a2 = rA[2], a3 = rA[3];
            uint4 b0 = rB[0], b1 = rB[1], b2 = rB[2], b3 = rB[3];
            unsigned int newA = 0, newB = 0;
#pragma unroll
            for (int s = 0; s < G; ++s) {
                const uint4* F = (const uint4*)s_f[p][s];
                uint4 f0 = F[0], f1 = F[1], f2 = F[2], f3 = F[3];
                unsigned int hA =
                    (a0.x & f0.x) | (a0.y & f0.y) | (a0.z & f0.z) | (a0.w & f0.w) |
                    (a1.x & f1.x) | (a1.y & f1.y) | (a1.z & f1.z) | (a1.w & f1.w) |
                    (a2.x & f2.x) | (a2.y & f2.y) | (a2.z & f2.z) | (a2.w & f2.w) |
                    (a3.x & f3.x) | (a3.y & f3.y) | (a3.z & f3.z) | (a3.w & f3.w);
                unsigned int hB =
                    (b0.x & f0.x) | (b0.y & f0.y) | (b0.z & f0.z) | (b0.w & f0.w) |
                    (b1.x & f1.x) | (b1.y & f1.y) | (b1.z & f1.z) | (b1.w & f1.w) |
                    (b2.x & f2.x) | (b2.y & f2.y) | (b2.z & f2.z) | (b2.w & f2.w) |
                    (b3.x & f3.x) | (b3.y & f3.y) | (b3.z & f3.z) | (b3.w & f3.w);
                if (hA && !((reachA >> s) & 1u)) newA |= 1u << s;
                if (hB && !((reachB >> s) & 1u)) newB |= 1u << s;
            }
            unsigned long long anyAcc = 0;
#pragma unroll
            for (int s = 0; s < G; ++s) {
                unsigned long long nA = __ballot((newA >> s) & 1u);
                unsigned long long nB = __ballot((newB >> s) & 1u);
                anyAcc |= nA | nB;
                if ((t & 63) == 0) {
                    int wv = t >> 6;
                    s_f[p ^ 1][s][2 * wv]         = (unsigned int)nA;
                    s_f[p ^ 1][s][2 * wv + 1]     = (unsigned int)(nA >> 32);
                    s_f[p ^ 1][s][8 + 2 * wv]     = (unsigned int)nB;
                    s_f[p ^ 1][s][8 + 2 * wv + 1] = (unsigned int)(nB >> 32);
                }
            }
            bool dn = (!validA || ((reachA | newA) == 0xffu)) &&
                      (!validB || ((reachB | newB) == 0xffu));
            unsigned long long bD = __ballot(dn);
            if ((t & 63) == 0)
                s_state[p ^ 1][t >> 6] = ((anyAcc != 0ull) ? 1u : 0u) |
                                         ((bD == ~0ull) ? 2u : 0u);
#pragma unroll
            for (int s = 0; s < G; ++s) {
                if ((newA >> s) & 1u) {
                    if (s < 4) dwA0 = (dwA0 & ~(0xffu << (8 * s))) | ((unsigned)tt << (8 * s));
                    else       dwA1 = (dwA1 & ~(0xffu << (8 * (s - 4)))) | ((unsigned)tt << (8 * (s - 4)));
                }
                if ((newB >> s) & 1u) {
                    if (s < 4) dwB0 = (dwB0 & ~(0xffu << (8 * s))) | ((unsigned)tt << (8 * s));
                    else       dwB1 = (dwB1 & ~(0xffu << (8 * (s - 4)))) | ((unsigned)tt << (8 * (s - 4)));
                }
            }
            reachA |= newA; reachB |= newB;
            __syncthreads();
            p ^= 1;
            unsigned int aw = 0, dw = 2;
#pragma unroll
            for (int wv = 0; wv < 4; ++wv) {
                unsigned int st = s_state[p][wv];
                aw |= st; dw &= st;
            }
            if (!(aw & 1u) || (dw & 2u)) break;
        }
        s_dw0[cA] = dwA0; s_dw1[cA] = dwA1;
        s_dw0[cB] = dwB0; s_dw1[cB] = dwB1;
    }
    __syncthreads();   // s_dw final for epilogue

    // Epilogue: 32 lane-contiguous float4 stores (8 sources x 4 chunks).
    const float4* e4 = (const float4*)s_emb;
    size_t base0 = ((size_t)b * NODES + i0) * (NODES * NOUT / 4); // 1024 f4/row
#pragma unroll
    for (int q = 0; q < 4; ++q) {
        int k = t + 256 * q;
        int half = k & 1;
        unsigned int w0 = s_dw0[k >> 1];
        unsigned int w1 = s_dw1[k >> 1];
#pragma unroll
        for (int s = 0; s < G; ++s) {
            int d = (int)((s < 4 ? w0 >> (8 * s) : w1 >> (8 * (s - 4))) & 0xffu);
            out4[base0 + (size_t)s * 1024 + k] = e4[2 * d + half];
        }
    }
}

// ---------------------------------------------------------------------------
extern "C" void kernel_launch(void* const* d_in, const int* in_sizes, int n_in,
                              void* d_out, int out_size, void* d_ws, size_t ws_size,
                              hipStream_t stream) {
    const float* adjacency = (const float*)d_in[0];
    const int* node_mask = (const int*)d_in[1];   // bool -> int32 on upload
    const float* emb = (const float*)d_in[2];
    float4* out4 = (float4*)d_out;

    unsigned int* bitA = (unsigned int*)d_ws;                       // 1 MB
    unsigned int* adjb = bitA + (size_t)NBATCH * NODES * WORDS;     // 1 MB

    // K1: 262144 words -> 1024 blocks (each thread packs 32 adjacency elems)
    pack_bits<<<1024, 256, 0, stream>>>(adjacency, node_mask, bitA);
    // K2: 262144 words -> 1024 blocks
    symmetrize<<<1024, 256, 0, stream>>>(bitA, adjb);
    // K3: one block per (8 sources, batch) = 2048 blocks, exactly 8/CU
    bfs_store<<<dim3(NODES / G, NBATCH), 256, 0, stream>>>(adjb, node_mask, emb, out4);
}

// Round 11
// 96.250 us; speedup vs baseline: 1.5407x; 1.5407x over previous
//
#include <hip/hip_runtime.h>

#define NODES 512
#define WORDS 16          // 512 bits / 32
#define NBATCH 32
#define SENTINEL 11       // MAX_DISTANCE + 1
#define NEMB 12           // MAX_DISTANCE + 2
#define NOUT 8
#define G 8               // sources per bfs_dist block

// ---------------------------------------------------------------------------
// K1: pack adjacency bits, one u32 word (32 elements, 8x float4) per thread.
// node_mask (int32 on upload) ballot-packed into LDS once per block.
// ---------------------------------------------------------------------------
__global__ void __launch_bounds__(256)
pack_bits(const float* __restrict__ A, const int* __restrict__ mask,
          unsigned int* __restrict__ bitA) {
    const int tid = blockIdx.x * 256 + threadIdx.x;   // 262144 words total
    const int t = threadIdx.x;
    const int w = tid & 15;
    const int i = (tid >> 4) & 511;
    const int b = tid >> 13;                          // constant per block

    __shared__ unsigned int s_mw[WORDS];
    {
        bool m0 = mask[b * NODES + t] != 0;
        bool m1 = mask[b * NODES + 256 + t] != 0;
        unsigned long long b0 = __ballot(m0);
        unsigned long long b1 = __ballot(m1);
        if ((t & 63) == 0) {
            int wv = t >> 6;
            s_mw[2 * wv]         = (unsigned int)b0;
            s_mw[2 * wv + 1]     = (unsigned int)(b0 >> 32);
            s_mw[8 + 2 * wv]     = (unsigned int)b1;
            s_mw[8 + 2 * wv + 1] = (unsigned int)(b1 >> 32);
        }
    }

    const float4* p = (const float4*)(A + (size_t)tid * 32);
    unsigned int bits = 0;
#pragma unroll
    for (int q = 0; q < 8; ++q) {
        float4 v = p[q];
        bits |= (v.x > 0.5f ? 1u : 0u) << (4 * q);
        bits |= (v.y > 0.5f ? 1u : 0u) << (4 * q + 1);
        bits |= (v.z > 0.5f ? 1u : 0u) << (4 * q + 2);
        bits |= (v.w > 0.5f ? 1u : 0u) << (4 * q + 3);
    }
    __syncthreads();
    bool rv = (s_mw[i >> 5] >> (i & 31)) & 1u;
    bitA[tid] = rv ? (bits & s_mw[w]) : 0u;
}

// ---------------------------------------------------------------------------
// K2: symmetrize: adj[b,i,w] |= transpose bits (1 MB, L2-resident).
// ---------------------------------------------------------------------------
__global__ void __launch_bounds__(256)
symmetrize(const unsigned int* __restrict__ bitA, unsigned int* __restrict__ adjb) {
    int tid = blockIdx.x * 256 + threadIdx.x;   // total B*N*WORDS = 262144
    int w = tid & 15;
    int i = (tid >> 4) & 511;
    int b = tid >> 13;
    const unsigned int* base = bitA + (size_t)b * NODES * WORDS;
    unsigned int word = base[i * WORDS + w];
    unsigned int t = 0;
    int iw = i >> 5, ib = i & 31;
#pragma unroll
    for (int k = 0; k < 32; ++k) {
        t |= ((base[(32 * w + k) * WORDS + iw] >> ib) & 1u) << k;
    }
    adjb[tid] = word | t;
}

// ---------------------------------------------------------------------------
// K3: direct d<=2 distance computation -> dist8 byte matrix. G=8 sources per
// block, 256 threads (cols t and t+256 sequentially). (256,4)=128 VGPR: the
// cold fallback's live set FITS (round 10 spilled at the 64-VGPR cap: +69us).
// Hot path: d1 = bit of s_rowi (LDS broadcast), d2 = row_c & row_i != 0.
// Cold general BFS (t>=3) kept for correctness; never runs on dense inputs.
// ---------------------------------------------------------------------------
__global__ void __launch_bounds__(256, 4)
bfs_dist(const unsigned int* __restrict__ adjb, const int* __restrict__ mask,
         unsigned char* __restrict__ dist8) {
    const int i0 = blockIdx.x * G;
    const int b = blockIdx.y;
    const int t = threadIdx.x;
    const int cA = t, cB = t + 256;

    __shared__ unsigned int s_rowi[G][WORDS];      // 512 B source rows
    __shared__ unsigned int s_f[2][G][WORDS];      // frontier (fallback)
    __shared__ unsigned int s_state[2][4];

    const unsigned int* Ab = adjb + (size_t)b * NODES * WORDS;
    if (t < G * 4) {                               // 32 threads: 8 rows x 16B
        int s = t >> 2, q = t & 3;
        ((uint4*)s_rowi[s])[q] = ((const uint4*)(Ab + (size_t)(i0 + s) * WORDS))[q];
    }

    bool vs[G];
#pragma unroll
    for (int s = 0; s < G; ++s) vs[s] = (mask[b * NODES + i0 + s] != 0);
    const bool validA = (mask[b * NODES + cA] != 0);
    const bool validB = (mask[b * NODES + cB] != 0);

    const uint4* rA = (const uint4*)(Ab + (size_t)cA * WORDS);
    const uint4* rB = (const uint4*)(Ab + (size_t)cB * WORDS);

    __syncthreads();   // s_rowi visible

    unsigned int dwA0 = 0, dwA1 = 0, dwB0 = 0, dwB1 = 0;
    {   // column cA
        uint4 r0 = rA[0], r1 = rA[1], r2 = rA[2], r3 = rA[3];
#pragma unroll
        for (int s = 0; s < G; ++s) {
            const uint4* R = (const uint4*)s_rowi[s];   // broadcast reads
            uint4 R0 = R[0], R1 = R[1], R2 = R[2], R3 = R[3];
            unsigned int hit =
                (r0.x & R0.x) | (r0.y & R0.y) | (r0.z & R0.z) | (r0.w & R0.w) |
                (r1.x & R1.x) | (r1.y & R1.y) | (r1.z & R1.z) | (r1.w & R1.w) |
                (r2.x & R2.x) | (r2.y & R2.y) | (r2.z & R2.z) | (r2.w & R2.w) |
                (r3.x & R3.x) | (r3.y & R3.y) | (r3.z & R3.z) | (r3.w & R3.w);
            unsigned int bit1 = (s_rowi[s][cA >> 5] >> (cA & 31)) & 1u;
            unsigned int d = (cA == i0 + s && vs[s]) ? 0u
                             : (bit1 ? 1u : (hit ? 2u : (unsigned)SENTINEL));
            if (s < 4) dwA0 |= d << (8 * s); else dwA1 |= d << (8 * (s - 4));
        }
    }
    {   // column cB
        uint4 r0 = rB[0], r1 = rB[1], r2 = rB[2], r3 = rB[3];
#pragma unroll
        for (int s = 0; s < G; ++s) {
            const uint4* R = (const uint4*)s_rowi[s];
            uint4 R0 = R[0], R1 = R[1], R2 = R[2], R3 = R[3];
            unsigned int hit =
                (r0.x & R0.x) | (r0.y & R0.y) | (r0.z & R0.z) | (r0.w & R0.w) |
                (r1.x & R1.x) | (r1.y & R1.y) | (r1.z & R1.z) | (r1.w & R1.w) |
                (r2.x & R2.x) | (r2.y & R2.y) | (r2.z & R2.z) | (r2.w & R2.w) |
                (r3.x & R3.x) | (r3.y & R3.y) | (r3.z & R3.z) | (r3.w & R3.w);
            unsigned int bit1 = (s_rowi[s][cB >> 5] >> (cB & 31)) & 1u;
            unsigned int d = (cB == i0 + s && vs[s]) ? 0u
                             : (bit1 ? 1u : (hit ? 2u : (unsigned)SENTINEL));
            if (s < 4) dwB0 |= d << (8 * s); else dwB1 |= d << (8 * (s - 4));
        }
    }

    // consensus: seed d==2 frontier + saturation (d<=2 iff byte bit3 clear)
    {
        bool thr_done =
            (!validA || (((dwA0 | (dwA0 >> 16)) & 0x0808u) == 0 &&
                         ((dwA1 | (dwA1 >> 16)) & 0x0808u) == 0)) &&
            (!validB || (((dwB0 | (dwB0 >> 16)) & 0x0808u) == 0 &&
                         ((dwB1 | (dwB1 >> 16)) & 0x0808u) == 0));
        unsigned long long balD = __ballot(thr_done);
        unsigned long long anyAcc = 0;
#pragma unroll
        for (int s = 0; s < G; ++s) {
            unsigned int dA = ((s < 4 ? dwA0 >> (8 * s) : dwA1 >> (8 * (s - 4))) & 0xffu);
            unsigned int dB = ((s < 4 ? dwB0 >> (8 * s) : dwB1 >> (8 * (s - 4))) & 0xffu);
            unsigned long long fA = __ballot(dA == 2u);
            unsigned long long fB = __ballot(dB == 2u);
            anyAcc |= fA | fB;
            if ((t & 63) == 0) {
                int wv = t >> 6;
                s_f[0][s][2 * wv]         = (unsigned int)fA;
                s_f[0][s][2 * wv + 1]     = (unsigned int)(fA >> 32);
                s_f[0][s][8 + 2 * wv]     = (unsigned int)fB;
                s_f[0][s][8 + 2 * wv + 1] = (unsigned int)(fB >> 32);
            }
        }
        if ((t & 63) == 0)
            s_state[0][t >> 6] = ((anyAcc != 0ull) ? 1u : 0u) |
                                 ((balD == ~0ull) ? 2u : 0u);
    }
    __syncthreads();
    unsigned int anyw = 0, donew = 2;
#pragma unroll
    for (int wv = 0; wv < 4; ++wv) {
        unsigned int st = s_state[0][wv];
        anyw |= st; donew &= st;
    }

    if ((anyw & 1u) && !(donew & 2u)) {
        // COLD general BFS t=3..10 (double-buffered frontier).
        unsigned int reachA = 0, reachB = 0;
#pragma unroll
        for (int s = 0; s < G; ++s) {
            unsigned int dA = ((s < 4 ? dwA0 >> (8 * s) : dwA1 >> (8 * (s - 4))) & 0xffu);
            unsigned int dB = ((s < 4 ? dwB0 >> (8 * s) : dwB1 >> (8 * (s - 4))) & 0xffu);
            if (dA != (unsigned)SENTINEL) reachA |= 1u << s;
            if (dB != (unsigned)SENTINEL) reachB |= 1u << s;
        }
        int p = 0;
        for (int tt = 3; tt <= 10; ++tt) {
            uint4 a0 = rA[0], a1 = rA[1], a2 = rA[2], a3 = rA[3];
            uint4 b0 = rB[0], b1 = rB[1], b2 = rB[2], b3 = rB[3];
            unsigned int newA = 0, newB = 0;
#pragma unroll
            for (int s = 0; s < G; ++s) {
                const uint4* F = (const uint4*)s_f[p][s];
                uint4 f0 = F[0], f1 = F[1], f2 = F[2], f3 = F[3];
                unsigned int hA =
                    (a0.x & f0.x) | (a0.y & f0.y) | (a0.z & f0.z) | (a0.w & f0.w) |
                    (a1.x & f1.x) | (a1.y & f1.y) | (a1.z & f1.z) | (a1.w & f1.w) |
                    (a2.x & f2.x) | (a2.y & f2.y) | (a2.z & f2.z) | (a2.w & f2.w) |
                    (a3.x & f3.x) | (a3.y & f3.y) | (a3.z & f3.z) | (a3.w & f3.w);
                unsigned int hB =
                    (b0.x & f0.x) | (b0.y & f0.y) | (b0.z & f0.z) | (b0.w & f0.w) |
                    (b1.x & f1.x) | (b1.y & f1.y) | (b1.z & f1.z) | (b1.w & f1.w) |
                    (b2.x & f2.x) | (b2.y & f2.y) | (b2.z & f2.z) | (b2.w & f2.w) |
                    (b3.x & f3.x) | (b3.y & f3.y) | (b3.z & f3.z) | (b3.w & f3.w);
                if (hA && !((reachA >> s) & 1u)) newA |= 1u << s;
                if (hB && !((reachB >> s) & 1u)) newB |= 1u << s;
            }
            unsigned long long anyAcc = 0;
#pragma unroll
            for (int s = 0; s < G; ++s) {
                unsigned long long nA = __ballot((newA >> s) & 1u);
                unsigned long long nB = __ballot((newB >> s) & 1u);
                anyAcc |= nA | nB;
                if ((t & 63) == 0) {
                    int wv = t >> 6;
                    s_f[p ^ 1][s][2 * wv]         = (unsigned int)nA;
                    s_f[p ^ 1][s][2 * wv + 1]     = (unsigned int)(nA >> 32);
                    s_f[p ^ 1][s][8 + 2 * wv]     = (unsigned int)nB;
                    s_f[p ^ 1][s][8 + 2 * wv + 1] = (unsigned int)(nB >> 32);
                }
            }
            bool dn = (!validA || ((reachA | newA) == 0xffu)) &&
                      (!validB || ((reachB | newB) == 0xffu));
            unsigned long long bD = __ballot(dn);
            if ((t & 63) == 0)
                s_state[p ^ 1][t >> 6] = ((anyAcc != 0ull) ? 1u : 0u) |
                                         ((bD == ~0ull) ? 2u : 0u);
#pragma unroll
            for (int s = 0; s < G; ++s) {
                if ((newA >> s) & 1u) {
                    if (s < 4) dwA0 = (dwA0 & ~(0xffu << (8 * s))) | ((unsigned)tt << (8 * s));
                    else       dwA1 = (dwA1 & ~(0xffu << (8 * (s - 4)))) | ((unsigned)tt << (8 * (s - 4)));
                }
                if ((newB >> s) & 1u) {
                    if (s < 4) dwB0 = (dwB0 & ~(0xffu << (8 * s))) | ((unsigned)tt << (8 * s));
                    else       dwB1 = (dwB1 & ~(0xffu << (8 * (s - 4)))) | ((unsigned)tt << (8 * (s - 4)));
                }
            }
            reachA |= newA; reachB |= newB;
            __syncthreads();
            p ^= 1;
            unsigned int aw = 0, dw = 2;
#pragma unroll
            for (int wv = 0; wv < 4; ++wv) {
                unsigned int st = s_state[p][wv];
                aw |= st; dw &= st;
            }
            if (!(aw & 1u) || (dw & 2u)) break;
        }
    }

    // write dist bytes: per source row, lanes write consecutive bytes (64 B/wave)
    unsigned char* drow = dist8 + (size_t)b * NODES * NODES;
#pragma unroll
    for (int s = 0; s < G; ++s) {
        unsigned int dA = ((s < 4 ? dwA0 >> (8 * s) : dwA1 >> (8 * (s - 4))) & 0xffu);
        unsigned int dB = ((s < 4 ? dwB0 >> (8 * s) : dwB1 >> (8 * (s - 4))) & 0xffu);
        drow[(size_t)(i0 + s) * NODES + cA] = (unsigned char)dA;
        drow[(size_t)(i0 + s) * NODES + cB] = (unsigned char)dB;
    }
}

// ---------------------------------------------------------------------------
// K4: fill-mimicking streaming expand. 2048 blocks x 256 threads; block = 8
// output rows (128 KB). Stage 4 KB of dist bytes to LDS (one uint4/thread),
// then 32 INDEPENDENT lane-contiguous float4 stores per thread (512 B/thread
// store depth — 8x the fused kernels). Dist reads as u32 broadcasts
// (8 lanes/same dword -> conflict-free). ~16 VGPR, no launch cap.
// ---------------------------------------------------------------------------
__global__ void __launch_bounds__(256)
expand(const unsigned char* __restrict__ dist8, const float* __restrict__ emb,
       float4* __restrict__ out4) {
    const int t = threadIdx.x;
    __shared__ __align__(16) unsigned char s_d[4096];
    __shared__ __align__(16) float s_emb[NEMB * NOUT];

    if (t < NEMB * NOUT) s_emb[t] = emb[t];
    ((uint4*)s_d)[t] = ((const uint4*)(dist8 + (size_t)blockIdx.x * 4096))[t];
    __syncthreads();

    const float4* e4 = (const float4*)s_emb;
    const unsigned int* sd32 = (const unsigned int*)s_d;
    size_t base = (size_t)blockIdx.x * 8192;   // 8 rows x 1024 f4
#pragma unroll
    for (int q = 0; q < 32; ++q) {
        int k = q * 256 + t;
        unsigned int wd = sd32[q * 32 + (t >> 3)];        // broadcast read
        int d = (int)((wd >> (8 * ((t >> 1) & 3))) & 0xffu);
        out4[base + k] = e4[2 * d + (k & 1)];
    }
}

// ---------------------------------------------------------------------------
extern "C" void kernel_launch(void* const* d_in, const int* in_sizes, int n_in,
                              void* d_out, int out_size, void* d_ws, size_t ws_size,
                              hipStream_t stream) {
    const float* adjacency = (const float*)d_in[0];
    const int* node_mask = (const int*)d_in[1];   // bool -> int32 on upload
    const float* emb = (const float*)d_in[2];
    float4* out4 = (float4*)d_out;

    unsigned int* bitA = (unsigned int*)d_ws;                       // 1 MB
    unsigned int* adjb = bitA + (size_t)NBATCH * NODES * WORDS;     // 1 MB
    unsigned char* dist8 = (unsigned char*)(adjb + (size_t)NBATCH * NODES * WORDS); // 8 MB

    // K1: 262144 words -> 1024 blocks
    pack_bits<<<1024, 256, 0, stream>>>(adjacency, node_mask, bitA);
    // K2: 262144 words -> 1024 blocks
    symmetrize<<<1024, 256, 0, stream>>>(bitA, adjb);
    // K3: one block per (8 sources, batch) = 2048 blocks
    bfs_dist<<<dim3(NODES / G, NBATCH), 256, 0, stream>>>(adjb, node_mask, dist8);
    // K4: 2048 blocks x 8 rows, deep store streams
    expand<<<2048, 256, 0, stream>>>(dist8, emb, out4);
}